// Round 4
// baseline (693.331 us; speedup 1.0000x reference)
//
#include <hip/hip_runtime.h>
#include <float.h>

// Grid dims from the reference
#define BDIM 4
#define ZDIM 6
#define YDIM 200
#define XDIM 176
#define CDIM 64
#define KSLOTS (BDIM * ZDIM * YDIM * XDIM)  // 844800 (divisible by 64 and 256)

typedef float f32x4 __attribute__((ext_vector_type(4)));

__device__ __forceinline__ int voxel_key4(const int4 c) {
    return ((c.x * ZDIM + c.y) * YDIM + c.z) * XDIM + c.w;
}

__device__ __forceinline__ f32x4 vmax4(f32x4 a, f32x4 b) {
    f32x4 r;
    r.x = fmaxf(a.x, b.x); r.y = fmaxf(a.y, b.y);
    r.z = fmaxf(a.z, b.z); r.w = fmaxf(a.w, b.w);
    return r;
}

// ---------------- CSR build ----------------

// One kernel histograms both coord arrays.
__global__ void hist2_kernel(const int* __restrict__ c1, int n1, int* __restrict__ cnt1,
                             const int* __restrict__ c2, int n2, int* __restrict__ cnt2) {
    int i = blockIdx.x * blockDim.x + threadIdx.x;
    if (i < n1) {
        int4 cc = *reinterpret_cast<const int4*>(c1 + (long long)i * 4);
        atomicAdd(&cnt1[voxel_key4(cc)], 1);
    } else if (i < n1 + n2) {
        int j = i - n1;
        int4 cc = *reinterpret_cast<const int4*>(c2 + (long long)j * 4);
        atomicAdd(&cnt2[voxel_key4(cc)], 1);
    }
}

// Base allocation without a global scan: per-wave exclusive scan of counts
// (shfl) + ONE atomicAdd per wave on a global cursor. Run placement order is
// nondeterministic across replays, but max is exact and per-voxel sums have
// <= a handful of terms (well inside tolerance). pos[v] = run start.
__global__ void alloc2_kernel(const int* __restrict__ cnt1, int* __restrict__ pos1,
                              const int* __restrict__ cnt2, int* __restrict__ pos2,
                              int* __restrict__ gc) {
    int gid = blockIdx.x * blockDim.x + threadIdx.x;  // grid == 2*KSLOTS exactly
    const int* cnt; int* pos; int* g; int i;
    if (gid < KSLOTS) { cnt = cnt1; pos = pos1; g = gc;     i = gid; }
    else              { cnt = cnt2; pos = pos2; g = gc + 1; i = gid - KSLOTS; }
    // KSLOTS % 64 == 0, so a wave never straddles the two arrays.
    int c = cnt[i];
    int lane = threadIdx.x & 63;
    int x = c;  // inclusive wave scan
    #pragma unroll
    for (int off = 1; off < 64; off <<= 1) {
        int y = __shfl_up(x, off, 64);
        if (lane >= off) x += y;
    }
    int total = __shfl(x, 63, 64);
    int base = 0;
    if (lane == 63) base = atomicAdd(g, total);
    base = __shfl(base, 63, 64);
    pos[i] = base + x - c;  // wave base + exclusive prefix
}

// Scatter both point sets into CSR slots; pos[] is the cursor, so afterwards
// pos[v] == run END (begin = end - cnt[v]).
__global__ void scatter2_kernel(const int* __restrict__ c1, int n1,
                                int* __restrict__ pos1, int* __restrict__ idx1,
                                const int* __restrict__ c2, int n2,
                                int* __restrict__ pos2, int* __restrict__ idx2) {
    int i = blockIdx.x * blockDim.x + threadIdx.x;
    if (i < n1) {
        int4 cc = *reinterpret_cast<const int4*>(c1 + (long long)i * 4);
        int slot = atomicAdd(&pos1[voxel_key4(cc)], 1);
        idx1[slot] = i;
    } else if (i < n1 + n2) {
        int j = i - n1;
        int4 cc = *reinterpret_cast<const int4*>(c2 + (long long)j * 4);
        int slot = atomicAdd(&pos2[voxel_key4(cc)], 1);
        idx2[slot] = j;
    }
}

// ---------------- fused output pass ----------------
// One thread per (voxel, half-row): 32 channels in registers. Lane pairs
// (2v,2v+1) walk the same run -> each gathered row is one contiguous 256B
// read across the pair; a wave keeps up to 64 half-rows (16KB) in flight.
__global__ __launch_bounds__(256) void fuse_kernel(
        const float* __restrict__ f1, const int* __restrict__ idx1,
        const int* __restrict__ pos1, const int* __restrict__ cnt1,
        const float* __restrict__ f2, const int* __restrict__ idx2,
        const int* __restrict__ pos2, const int* __restrict__ cnt2,
        float* __restrict__ out) {
    int gid = blockIdx.x * blockDim.x + threadIdx.x;  // grid == 2*KSLOTS exactly
    int v = gid >> 1;
    int h = gid & 1;
    const float* fh2 = f2 + h * 32;
    const float* fh1 = f1 + h * 32;

    int e2 = pos2[v], r2 = cnt2[v], b2 = e2 - r2;
    int e1 = pos1[v], r1 = cnt1[v], b1 = e1 - r1;

    f32x4 am[8];
    #pragma unroll
    for (int k = 0; k < 8; ++k) am[k] = (f32x4)(-FLT_MAX);

    int j = b2;
    for (; j + 2 <= e2; j += 2) {
        int p0 = idx2[j], p1 = idx2[j + 1];
        const f32x4* r0 = (const f32x4*)(fh2 + (long long)p0 * CDIM);
        const f32x4* q1 = (const f32x4*)(fh2 + (long long)p1 * CDIM);
        #pragma unroll
        for (int k = 0; k < 8; ++k) {
            f32x4 a = r0[k], b = q1[k];
            am[k] = vmax4(am[k], vmax4(a, b));
        }
    }
    if (j < e2) {
        int p0 = idx2[j];
        const f32x4* r0 = (const f32x4*)(fh2 + (long long)p0 * CDIM);
        #pragma unroll
        for (int k = 0; k < 8; ++k) am[k] = vmax4(am[k], r0[k]);
    }
    if (r2 == 0) {
        #pragma unroll
        for (int k = 0; k < 8; ++k) am[k] = (f32x4)(0.f);
    }

    f32x4 as[8];
    #pragma unroll
    for (int k = 0; k < 8; ++k) as[k] = (f32x4)(0.f);

    j = b1;
    for (; j + 2 <= e1; j += 2) {
        int p0 = idx1[j], p1 = idx1[j + 1];
        const f32x4* r0 = (const f32x4*)(fh1 + (long long)p0 * CDIM);
        const f32x4* q1 = (const f32x4*)(fh1 + (long long)p1 * CDIM);
        #pragma unroll
        for (int k = 0; k < 8; ++k) as[k] += r0[k] + q1[k];
    }
    if (j < e1) {
        int p0 = idx1[j];
        const f32x4* r0 = (const f32x4*)(fh1 + (long long)p0 * CDIM);
        #pragma unroll
        for (int k = 0; k < 8; ++k) as[k] += r0[k];
    }

    f32x4* o = (f32x4*)(out + (long long)v * CDIM + h * 32);
    #pragma unroll
    for (int k = 0; k < 8; ++k)
        __builtin_nontemporal_store(am[k] + as[k], o + k);
}

// ---------------- fallback (atomic path, used only if ws too small) ----------

__device__ __forceinline__ unsigned ord_enc(float f) {
    unsigned u = __float_as_uint(f);
    return (u & 0x80000000u) ? ~u : (u | 0x80000000u);
}
__device__ __forceinline__ float ord_dec(unsigned u) {
    return (u & 0x80000000u) ? __uint_as_float(u & 0x7FFFFFFFu)
                             : __uint_as_float(~u);
}
__global__ void fb_scatter_max(const float* __restrict__ feats, const int* __restrict__ coords,
                               unsigned* __restrict__ out, int npts) {
    long long i = (long long)blockIdx.x * blockDim.x + threadIdx.x;
    if (i >= (long long)npts * (CDIM / 4)) return;
    int pt = (int)(i >> 4), c4 = (int)(i & 15);
    int4 cc = *reinterpret_cast<const int4*>(coords + (long long)pt * 4);
    int key = voxel_key4(cc);
    float4 f = *reinterpret_cast<const float4*>(feats + (long long)pt * CDIM + c4 * 4);
    unsigned* dst = out + (long long)key * CDIM + c4 * 4;
    atomicMax(dst + 0, ord_enc(f.x));
    atomicMax(dst + 1, ord_enc(f.y));
    atomicMax(dst + 2, ord_enc(f.z));
    atomicMax(dst + 3, ord_enc(f.w));
}
__global__ void fb_decode(unsigned* __restrict__ buf, long long n4) {
    long long i = (long long)blockIdx.x * blockDim.x + threadIdx.x;
    if (i >= n4) return;
    uint4 u = reinterpret_cast<const uint4*>(buf)[i];
    float4 f;
    f.x = (u.x == 0u) ? 0.f : ord_dec(u.x);
    f.y = (u.y == 0u) ? 0.f : ord_dec(u.y);
    f.z = (u.z == 0u) ? 0.f : ord_dec(u.z);
    f.w = (u.w == 0u) ? 0.f : ord_dec(u.w);
    reinterpret_cast<float4*>(buf)[i] = f;
}
__global__ void fb_scatter_add(const float* __restrict__ feats, const int* __restrict__ coords,
                               float* __restrict__ out, int npts) {
    long long i = (long long)blockIdx.x * blockDim.x + threadIdx.x;
    if (i >= (long long)npts * (CDIM / 4)) return;
    int pt = (int)(i >> 4), c4 = (int)(i & 15);
    int4 cc = *reinterpret_cast<const int4*>(coords + (long long)pt * 4);
    int key = voxel_key4(cc);
    float4 f = *reinterpret_cast<const float4*>(feats + (long long)pt * CDIM + c4 * 4);
    float* dst = out + (long long)key * CDIM + c4 * 4;
    atomicAdd(dst + 0, f.x); atomicAdd(dst + 1, f.y);
    atomicAdd(dst + 2, f.z); atomicAdd(dst + 3, f.w);
}

extern "C" void kernel_launch(void* const* d_in, const int* in_sizes, int n_in,
                              void* d_out, int out_size, void* d_ws, size_t ws_size,
                              hipStream_t stream) {
    const float* feats1 = (const float*)d_in[0];
    const int*   coords1 = (const int*)d_in[1];
    const float* feats2 = (const float*)d_in[2];
    const int*   coords2 = (const int*)d_in[3];
    float* out = (float*)d_out;

    const int n1 = in_sizes[1] / 4;
    const int n2 = in_sizes[3] / 4;
    const long long kc = (long long)KSLOTS * CDIM;

    const size_t needed = ((size_t)4 * KSLOTS + 2 + n1 + n2) * sizeof(int);
    if (ws_size < needed) {
        hipMemsetAsync(d_out, 0, kc * sizeof(float), stream);
        long long t2 = (long long)n2 * (CDIM / 4);
        fb_scatter_max<<<(int)((t2 + 255) / 256), 256, 0, stream>>>(feats2, coords2,
                                                                    (unsigned*)out, n2);
        long long q = kc / 4;
        fb_decode<<<(int)((q + 255) / 256), 256, 0, stream>>>((unsigned*)out, q);
        long long t1 = (long long)n1 * (CDIM / 4);
        fb_scatter_add<<<(int)((t1 + 255) / 256), 256, 0, stream>>>(feats1, coords1, out, n1);
        return;
    }

    // ws layout: cnt1 | cnt2 | gc[2] | pos1 | pos2 | idx1 | idx2
    int* cnt1 = (int*)d_ws;
    int* cnt2 = cnt1 + KSLOTS;
    int* gc   = cnt2 + KSLOTS;
    int* pos1 = gc + 2;
    int* pos2 = pos1 + KSLOTS;
    int* idx1 = pos2 + KSLOTS;
    int* idx2 = idx1 + n1;

    // zero counts + global cursors (contiguous)
    hipMemsetAsync(cnt1, 0, ((size_t)2 * KSLOTS + 2) * sizeof(int), stream);

    int nb12 = (n1 + n2 + 255) / 256;
    hist2_kernel<<<nb12, 256, 0, stream>>>(coords1, n1, cnt1, coords2, n2, cnt2);

    alloc2_kernel<<<2 * KSLOTS / 256, 256, 0, stream>>>(cnt1, pos1, cnt2, pos2, gc);

    scatter2_kernel<<<nb12, 256, 0, stream>>>(coords1, n1, pos1, idx1,
                                              coords2, n2, pos2, idx2);

    fuse_kernel<<<2 * KSLOTS / 256, 256, 0, stream>>>(
        feats1, idx1, pos1, cnt1, feats2, idx2, pos2, cnt2, out);
}

// Round 5
// 240.248 us; speedup vs baseline: 2.8859x; 2.8859x over previous
//
#include <hip/hip_runtime.h>
#include <float.h>

// Grid dims from the reference
#define BDIM 4
#define ZDIM 6
#define YDIM 200
#define XDIM 176
#define CDIM 64
#define KSLOTS (BDIM * ZDIM * YDIM * XDIM)  // 844800 (divisible by 64 and 256)
#define KS2 (2 * KSLOTS)                    // 1689600
#define SCAN_W 1024
#define NSCAN1 (KS2 / SCAN_W)               // 1650 (exact)

typedef float f32x4 __attribute__((ext_vector_type(4)));

__device__ __forceinline__ int voxel_key4(const int4 c) {
    return ((c.x * ZDIM + c.y) * YDIM + c.z) * XDIM + c.w;
}

__device__ __forceinline__ f32x4 vmax4(f32x4 a, f32x4 b) {
    f32x4 r;
    r.x = fmaxf(a.x, b.x); r.y = fmaxf(a.y, b.y);
    r.z = fmaxf(a.z, b.z); r.w = fmaxf(a.w, b.w);
    return r;
}

// ---------------- CSR build (unified cnt/pos over both sets) ----------------

// Histogram both coord arrays into one cnt[KS2] (set2 at offset KSLOTS).
__global__ void hist2_kernel(const int* __restrict__ c1, int n1,
                             const int* __restrict__ c2, int n2,
                             int* __restrict__ cnt) {
    int i = blockIdx.x * blockDim.x + threadIdx.x;
    if (i < n1) {
        int4 cc = *reinterpret_cast<const int4*>(c1 + (long long)i * 4);
        atomicAdd(&cnt[voxel_key4(cc)], 1);
    } else if (i < n1 + n2) {
        int j = i - n1;
        int4 cc = *reinterpret_cast<const int4*>(c2 + (long long)j * 4);
        atomicAdd(&cnt[KSLOTS + voxel_key4(cc)], 1);
    }
}

// Level-1: block-exclusive scan via wave-shfl + LDS combine (2 barriers).
__global__ void scan1_kernel(const int* __restrict__ cnt, int* __restrict__ pos,
                             int* __restrict__ bsum) {
    __shared__ int wsum[16];
    int t = threadIdx.x;
    int g = blockIdx.x * SCAN_W + t;
    int c = cnt[g];
    int lane = t & 63, wid = t >> 6;
    int x = c;
    #pragma unroll
    for (int off = 1; off < 64; off <<= 1) {
        int y = __shfl_up(x, off, 64);
        if (lane >= off) x += y;
    }
    if (lane == 63) wsum[wid] = x;
    __syncthreads();
    if (t < 16) {
        int w = wsum[t];
        int xx = w;
        #pragma unroll
        for (int off = 1; off < 16; off <<= 1) {
            int y = __shfl_up(xx, off, 16);
            if (t >= off) xx += y;
        }
        wsum[t] = xx - w;  // exclusive wave offset
        if (t == 15) bsum[blockIdx.x] = xx;
    }
    __syncthreads();
    pos[g] = wsum[wid] + x - c;
}

// Level-2: one block scans the 1650 block sums (2 elems/thread, exclusive).
__global__ void scan2_kernel(int* __restrict__ bsum, int nb) {
    __shared__ int wsum[16];
    int t = threadIdx.x;
    int a = (2 * t     < nb) ? bsum[2 * t]     : 0;
    int b = (2 * t + 1 < nb) ? bsum[2 * t + 1] : 0;
    int s = a + b;
    int lane = t & 63, wid = t >> 6;
    int x = s;
    #pragma unroll
    for (int off = 1; off < 64; off <<= 1) {
        int y = __shfl_up(x, off, 64);
        if (lane >= off) x += y;
    }
    if (lane == 63) wsum[wid] = x;
    __syncthreads();
    if (t < 16) {
        int w = wsum[t];
        int xx = w;
        #pragma unroll
        for (int off = 1; off < 16; off <<= 1) {
            int y = __shfl_up(xx, off, 16);
            if (t >= off) xx += y;
        }
        wsum[t] = xx - w;
    }
    __syncthreads();
    int ex = wsum[wid] + x - s;  // exclusive prefix of s
    if (2 * t     < nb) bsum[2 * t]     = ex;
    if (2 * t + 1 < nb) bsum[2 * t + 1] = ex + a;
}

// Level-3: add block offsets; write rowptr AND cursor copy; seal pos[KS2].
__global__ void scan3_kernel(int* __restrict__ pos, int* __restrict__ cur,
                             const int* __restrict__ bsum, int n12) {
    int g = blockIdx.x * SCAN_W + threadIdx.x;
    int v = pos[g] + bsum[blockIdx.x];
    pos[g] = v;
    cur[g] = v;
    if (g == 0) pos[KS2] = n12;
}

// Scatter both point sets into the unified idx array via cursors.
__global__ void scatter2_kernel(const int* __restrict__ c1, int n1,
                                const int* __restrict__ c2, int n2,
                                int* __restrict__ cur, int* __restrict__ idx) {
    int i = blockIdx.x * blockDim.x + threadIdx.x;
    if (i < n1) {
        int4 cc = *reinterpret_cast<const int4*>(c1 + (long long)i * 4);
        int slot = atomicAdd(&cur[voxel_key4(cc)], 1);
        idx[slot] = i;
    } else if (i < n1 + n2) {
        int j = i - n1;
        int4 cc = *reinterpret_cast<const int4*>(c2 + (long long)j * 4);
        int slot = atomicAdd(&cur[KSLOTS + voxel_key4(cc)], 1);
        idx[slot] = j;
    }
}

// ---------------- fused output pass ----------------
// 16 threads per voxel (c4 quads, lane-contiguous full-line nt stores), but
// each thread serves TWO voxels (va, vb=va+K/2) and walks SIX independent
// gather streams branchlessly: run2(va) x2, run2(vb) x2, run1(va), run1(vb).
// Clamped addresses keep dead lanes on cached lines; selects mask them out.
__global__ __launch_bounds__(256) void fuse_kernel(
        const float* __restrict__ f1, const float* __restrict__ f2,
        const int* __restrict__ idx, const int* __restrict__ pos,
        int n1, int n12, float* __restrict__ out) {
    int gid = blockIdx.x * blockDim.x + threadIdx.x;  // grid == KSLOTS/2*16
    int va = gid >> 4;
    int vb = va + KSLOTS / 2;
    int c4 = gid & 15;

    int b1a = pos[va],          e1a = pos[va + 1];
    int b1b = pos[vb],          e1b = pos[vb + 1];
    int b2a = pos[KSLOTS + va], e2a = pos[KSLOTS + va + 1];
    int b2b = pos[KSLOTS + vb], e2b = pos[KSLOTS + vb + 1];

    f32x4 ma = (f32x4)(-FLT_MAX), mb = (f32x4)(-FLT_MAX);
    f32x4 sa = (f32x4)(0.f),      sb = (f32x4)(0.f);

    int j1a = b1a, j1b = b1b, j2a = b2a, j2b = b2b;
    const int nm1 = n1 - 1, nm12 = n12 - 1;

    while ((j2a < e2a) | (j2b < e2b) | (j1a < e1a) | (j1b < e1b)) {
        bool u0 = j2a < e2a,     u1 = (j2a + 1) < e2a;
        bool w0 = j2b < e2b,     w1 = (j2b + 1) < e2b;
        bool y0 = j1a < e1a,     z0 = j1b < e1b;
        // six independent idx loads (clamped to valid region of each set)
        int pa0 = idx[min(j2a,     nm12)];
        int pa1 = idx[min(j2a + 1, nm12)];
        int pb0 = idx[min(j2b,     nm12)];
        int pb1 = idx[min(j2b + 1, nm12)];
        int q0  = idx[min(j1a,     nm1)];
        int q1  = idx[min(j1b,     nm1)];
        // six independent row loads
        f32x4 xa0 = *(const f32x4*)(f2 + (long long)pa0 * CDIM + c4 * 4);
        f32x4 xa1 = *(const f32x4*)(f2 + (long long)pa1 * CDIM + c4 * 4);
        f32x4 xb0 = *(const f32x4*)(f2 + (long long)pb0 * CDIM + c4 * 4);
        f32x4 xb1 = *(const f32x4*)(f2 + (long long)pb1 * CDIM + c4 * 4);
        f32x4 xq0 = *(const f32x4*)(f1 + (long long)q0  * CDIM + c4 * 4);
        f32x4 xq1 = *(const f32x4*)(f1 + (long long)q1  * CDIM + c4 * 4);
        ma = u0 ? vmax4(ma, xa0) : ma;
        ma = u1 ? vmax4(ma, xa1) : ma;
        mb = w0 ? vmax4(mb, xb0) : mb;
        mb = w1 ? vmax4(mb, xb1) : mb;
        sa = y0 ? (sa + xq0) : sa;
        sb = z0 ? (sb + xq1) : sb;
        j2a += (int)u0 + (int)u1;
        j2b += (int)w0 + (int)w1;
        j1a += (int)y0;
        j1b += (int)z0;
    }
    if (b2a == e2a) ma = (f32x4)(0.f);
    if (b2b == e2b) mb = (f32x4)(0.f);

    // lane-contiguous full-line nontemporal stores (1KB/instr per wave)
    __builtin_nontemporal_store(ma + sa,
        (f32x4*)(out + (long long)va * CDIM + c4 * 4));
    __builtin_nontemporal_store(mb + sb,
        (f32x4*)(out + (long long)vb * CDIM + c4 * 4));
}

// ---------------- fallback (atomic path, used only if ws too small) ----------

__device__ __forceinline__ unsigned ord_enc(float f) {
    unsigned u = __float_as_uint(f);
    return (u & 0x80000000u) ? ~u : (u | 0x80000000u);
}
__device__ __forceinline__ float ord_dec(unsigned u) {
    return (u & 0x80000000u) ? __uint_as_float(u & 0x7FFFFFFFu)
                             : __uint_as_float(~u);
}
__global__ void fb_scatter_max(const float* __restrict__ feats, const int* __restrict__ coords,
                               unsigned* __restrict__ out, int npts) {
    long long i = (long long)blockIdx.x * blockDim.x + threadIdx.x;
    if (i >= (long long)npts * (CDIM / 4)) return;
    int pt = (int)(i >> 4), c4 = (int)(i & 15);
    int4 cc = *reinterpret_cast<const int4*>(coords + (long long)pt * 4);
    int key = voxel_key4(cc);
    float4 f = *reinterpret_cast<const float4*>(feats + (long long)pt * CDIM + c4 * 4);
    unsigned* dst = out + (long long)key * CDIM + c4 * 4;
    atomicMax(dst + 0, ord_enc(f.x));
    atomicMax(dst + 1, ord_enc(f.y));
    atomicMax(dst + 2, ord_enc(f.z));
    atomicMax(dst + 3, ord_enc(f.w));
}
__global__ void fb_decode(unsigned* __restrict__ buf, long long n4) {
    long long i = (long long)blockIdx.x * blockDim.x + threadIdx.x;
    if (i >= n4) return;
    uint4 u = reinterpret_cast<const uint4*>(buf)[i];
    float4 f;
    f.x = (u.x == 0u) ? 0.f : ord_dec(u.x);
    f.y = (u.y == 0u) ? 0.f : ord_dec(u.y);
    f.z = (u.z == 0u) ? 0.f : ord_dec(u.z);
    f.w = (u.w == 0u) ? 0.f : ord_dec(u.w);
    reinterpret_cast<float4*>(buf)[i] = f;
}
__global__ void fb_scatter_add(const float* __restrict__ feats, const int* __restrict__ coords,
                               float* __restrict__ out, int npts) {
    long long i = (long long)blockIdx.x * blockDim.x + threadIdx.x;
    if (i >= (long long)npts * (CDIM / 4)) return;
    int pt = (int)(i >> 4), c4 = (int)(i & 15);
    int4 cc = *reinterpret_cast<const int4*>(coords + (long long)pt * 4);
    int key = voxel_key4(cc);
    float4 f = *reinterpret_cast<const float4*>(feats + (long long)pt * CDIM + c4 * 4);
    float* dst = out + (long long)key * CDIM + c4 * 4;
    atomicAdd(dst + 0, f.x); atomicAdd(dst + 1, f.y);
    atomicAdd(dst + 2, f.z); atomicAdd(dst + 3, f.w);
}

extern "C" void kernel_launch(void* const* d_in, const int* in_sizes, int n_in,
                              void* d_out, int out_size, void* d_ws, size_t ws_size,
                              hipStream_t stream) {
    const float* feats1 = (const float*)d_in[0];
    const int*   coords1 = (const int*)d_in[1];
    const float* feats2 = (const float*)d_in[2];
    const int*   coords2 = (const int*)d_in[3];
    float* out = (float*)d_out;

    const int n1 = in_sizes[1] / 4;
    const int n2 = in_sizes[3] / 4;
    const int n12 = n1 + n2;
    const long long kc = (long long)KSLOTS * CDIM;

    const size_t needed = ((size_t)KS2 + (KS2 + 1) + NSCAN1 + n12) * sizeof(int);
    if (ws_size < needed) {
        hipMemsetAsync(d_out, 0, kc * sizeof(float), stream);
        long long t2 = (long long)n2 * (CDIM / 4);
        fb_scatter_max<<<(int)((t2 + 255) / 256), 256, 0, stream>>>(feats2, coords2,
                                                                    (unsigned*)out, n2);
        long long q = kc / 4;
        fb_decode<<<(int)((q + 255) / 256), 256, 0, stream>>>((unsigned*)out, q);
        long long t1 = (long long)n1 * (CDIM / 4);
        fb_scatter_add<<<(int)((t1 + 255) / 256), 256, 0, stream>>>(feats1, coords1, out, n1);
        return;
    }

    // ws layout: cnt[KS2] (doubles as cursor) | pos[KS2+1] | bsum[NSCAN1] | idx[n12]
    int* cnt  = (int*)d_ws;
    int* pos  = cnt + KS2;
    int* bsum = pos + KS2 + 1;
    int* idx  = bsum + NSCAN1;

    hipMemsetAsync(cnt, 0, (size_t)KS2 * sizeof(int), stream);

    int nb12 = (n12 + 255) / 256;
    hist2_kernel<<<nb12, 256, 0, stream>>>(coords1, n1, coords2, n2, cnt);

    scan1_kernel<<<NSCAN1, SCAN_W, 0, stream>>>(cnt, pos, bsum);
    scan2_kernel<<<1, SCAN_W, 0, stream>>>(bsum, NSCAN1);
    scan3_kernel<<<NSCAN1, SCAN_W, 0, stream>>>(pos, cnt, bsum, n12);

    scatter2_kernel<<<nb12, 256, 0, stream>>>(coords1, n1, coords2, n2, cnt, idx);

    fuse_kernel<<<KSLOTS / 32, 256, 0, stream>>>(feats1, feats2, idx, pos, n1, n12, out);
}